// Round 8
// baseline (279.394 us; speedup 1.0000x reference)
//
#include <hip/hip_runtime.h>
#include <cstddef>

typedef __bf16 bf16_t;
typedef __bf16 bf16x8 __attribute__((ext_vector_type(8)));
typedef __bf16 bf16x4 __attribute__((ext_vector_type(4)));
typedef float  f32x4  __attribute__((ext_vector_type(4)));

// Problem constants: B=2, T=2048, D=1024, H=16, K=V=64, W=256
// ---------------------------------------------------------------------------
// PREP megakernel (1 launch, 10496 blocks x 256 thr):
//   blocks [0,6144)    : fp32->bf16 convert of 6 weight matrices (w/ scale)
//   blocks [6144,6400) : RoPE cos/sin table (2048 x 32 float2)
//   blocks [6400,10496): RMSNorm + bf16 cast + gate mean + d_out := x
struct CvtArgs { const float* s[6]; bf16_t* d[6]; float scale[6]; };
__global__ __launch_bounds__(256) void prep_kernel(CvtArgs ca,
                                                   const float* __restrict__ x,
                                                   const float* __restrict__ nw,
                                                   const float* __restrict__ wg,
                                                   const float* __restrict__ bg,
                                                   bf16_t* __restrict__ xn,
                                                   float* __restrict__ gm,
                                                   float2* __restrict__ rtab,
                                                   float* __restrict__ dout) {
  __shared__ float red[4];
  __shared__ float gred[4][16];
  int bid = blockIdx.x;
  int tid = threadIdx.x;
  if (bid < 6144) {
    int m = bid >> 10;
    int i = (bid & 1023) * 256 + tid;        // 262144 f32x4 per matrix
    f32x4 v = ((const f32x4*)ca.s[m])[i];
    float sc = ca.scale[m];
    bf16x4 o;
    #pragma unroll
    for (int j = 0; j < 4; ++j) o[j] = (bf16_t)(v[j] * sc);
    *(bf16x4*)(ca.d[m] + (size_t)i * 4) = o;
    return;
  }
  if (bid < 6400) {
    int i = (bid - 6144) * 256 + tid;        // 65536 = 2048*32
    int t = i >> 5, d = i & 31;
    float inv = exp2f((float)d * -0.41524101186092029f);  // 10000^(-d/32)
    float sn, cs;
    sincosf((float)t * inv, &sn, &cs);
    rtab[i] = make_float2(cs, sn);
    return;
  }
  int t = bid - 6400;                        // 4096 token rows
  int wave = tid >> 6, lane = tid & 63;
  f32x4 v = ((const f32x4*)(x + (size_t)t * 1024))[tid];
  ((f32x4*)(dout + (size_t)t * 1024))[tid] = v;   // residual pre-init
  float ss = v[0]*v[0] + v[1]*v[1] + v[2]*v[2] + v[3]*v[3];
  #pragma unroll
  for (int off = 32; off >= 1; off >>= 1) ss += __shfl_xor(ss, off);
  if (lane == 0) red[wave] = ss;
  __syncthreads();
  float tot = red[0] + red[1] + red[2] + red[3];
  float rinv = rsqrtf(tot * (1.0f / 1024.0f) + 1e-6f);
  f32x4 wv = ((const f32x4*)nw)[tid];
  float xnv[4];
  bf16x4 o;
  #pragma unroll
  for (int i = 0; i < 4; ++i) { xnv[i] = v[i] * rinv * wv[i]; o[i] = (bf16_t)xnv[i]; }
  *(bf16x4*)(xn + (size_t)t * 1024 + tid * 4) = o;
  float ga[16];
  #pragma unroll
  for (int h = 0; h < 16; ++h) {
    f32x4 wgh = ((const f32x4*)(wg + h * 1024))[tid];
    ga[h] = xnv[0]*wgh[0] + xnv[1]*wgh[1] + xnv[2]*wgh[2] + xnv[3]*wgh[3];
  }
  #pragma unroll
  for (int h = 0; h < 16; ++h) {
    #pragma unroll
    for (int off = 32; off >= 1; off >>= 1) ga[h] += __shfl_xor(ga[h], off);
  }
  if (lane < 16) gred[wave][lane] = ga[lane];
  __syncthreads();
  if (tid < 16) {
    float s = gred[0][tid] + gred[1][tid] + gred[2][tid] + gred[3][tid];
    float sig = 1.0f / (1.0f + __expf(-(s + bg[tid])));
    #pragma unroll
    for (int off = 8; off >= 1; off >>= 1) sig += __shfl_xor(sig, off);
    if (tid == 0) gm[t] = sig * (1.0f / 16.0f);
  }
}

// ---------------------------------------------------------------------------
// bf16 MFMA GEMM, C = A (M x KD) * W^T, W row-major (1024 x KD).
// 128x128 tile, 4 waves x (4x4) 16x16x32 MFMA. Template BK (32 or 64):
// BK=64 halves barrier count (32 MFMA/barrier). LDSK=BK+8 keeps rows
// 16B-aligned with 2-way bank aliasing (free, m136). Per-seg koff enables
// split-K (partials merged via fp32 atomic add epilogue).
// Runtime per-seg mode: 0 = bf16 out; 1 = bf16 + RoPE table; 3 = atomic fp32.
struct GemmSeg { const bf16_t* a; const bf16_t* w; void* c; int mode; int koff; };
struct GemmCfg { GemmSeg seg[4]; const float2* rope; };
template<int KD, int KLEN, int BK>
__global__ __launch_bounds__(256, 2) void gemm_bt(GemmCfg cfg) {
  constexpr int LDSK = BK + 8;
  constexpr int KC = BK / 8;                // 16B chunks per row
  __shared__ bf16_t As[128 * LDSK];
  __shared__ bf16_t Bs[128 * LDSK];
  int seg = blockIdx.x >> 3;
  const bf16_t* __restrict__ A = cfg.seg[seg].a;
  const bf16_t* __restrict__ W = cfg.seg[seg].w;
  int koff = cfg.seg[seg].koff;
  int m0 = blockIdx.y * 128;
  int n0 = (blockIdx.x & 7) * 128;
  int tid = threadIdx.x;
  int lane = tid & 63, wave = tid >> 6;
  int wm = (wave >> 1) * 64, wn = (wave & 1) * 64;
  int l16 = lane & 15, quad = lane >> 4;
  f32x4 acc[4][4] = {};
  for (int k0 = koff; k0 < koff + KLEN; k0 += BK) {
    __syncthreads();
    #pragma unroll
    for (int c = 0; c < BK / 16; ++c) {     // 128*KC chunks per matrix
      int ci = tid + c * 256;
      int r = ci / KC;
      int ko = (ci % KC) * 8;
      *(uint4*)&As[r * LDSK + ko] = *(const uint4*)&A[(size_t)(m0 + r) * KD + k0 + ko];
      *(uint4*)&Bs[r * LDSK + ko] = *(const uint4*)&W[(size_t)(n0 + r) * KD + k0 + ko];
    }
    __syncthreads();
    #pragma unroll
    for (int ks = 0; ks < BK / 32; ++ks) {
      bf16x8 af[4], bfr[4];
      #pragma unroll
      for (int i = 0; i < 4; ++i) {
        af[i]  = *(const bf16x8*)&As[(wm + i * 16 + l16) * LDSK + ks * 32 + quad * 8];
        bfr[i] = *(const bf16x8*)&Bs[(wn + i * 16 + l16) * LDSK + ks * 32 + quad * 8];
      }
      #pragma unroll
      for (int i = 0; i < 4; ++i)
        #pragma unroll
        for (int j = 0; j < 4; ++j)
          acc[i][j] = __builtin_amdgcn_mfma_f32_16x16x32_bf16(af[i], bfr[j], acc[i][j], 0, 0, 0);
    }
  }
  int mode = cfg.seg[seg].mode;
  // C/D layout: col = lane&15, row = quad*4 + reg
  if (mode == 1) {
    const float2* tab = cfg.rope;
    #pragma unroll
    for (int jp = 0; jp < 2; ++jp) {
      int d = jp * 16 + l16;
      #pragma unroll
      for (int i = 0; i < 4; ++i)
        #pragma unroll
        for (int r = 0; r < 4; ++r) {
          int tseq = (m0 + wm + i * 16 + quad * 4 + r) & 2047;
          float2 cz = tab[(tseq << 5) + d];
          float v1 = acc[i][jp][r], v2 = acc[i][jp + 2][r];
          acc[i][jp][r]     = v1 * cz.x - v2 * cz.y;
          acc[i][jp + 2][r] = v2 * cz.x + v1 * cz.y;
        }
    }
  }
  if (mode == 3) {
    float* C = (float*)cfg.seg[seg].c;
    #pragma unroll
    for (int i = 0; i < 4; ++i)
      #pragma unroll
      for (int j = 0; j < 4; ++j) {
        int row = m0 + wm + i * 16 + quad * 4;
        int col = n0 + wn + j * 16 + l16;
        #pragma unroll
        for (int r = 0; r < 4; ++r)
          unsafeAtomicAdd(&C[(size_t)(row + r) * 1024 + col], acc[i][j][r]);
      }
  } else {
    bf16_t* C = (bf16_t*)cfg.seg[seg].c;
    #pragma unroll
    for (int i = 0; i < 4; ++i)
      #pragma unroll
      for (int j = 0; j < 4; ++j) {
        int row = m0 + wm + i * 16 + quad * 4;
        int col = n0 + wn + j * 16 + l16;
        #pragma unroll
        for (int r = 0; r < 4; ++r)
          C[(size_t)(row + r) * 1024 + col] = (bf16_t)acc[i][j][r];
      }
  }
}

// ---------------------------------------------------------------------------
// Merged attention + retrieval (1 launch, 1280 blocks x 256 thr).
// blocks [0,1024): MFMA flash attention -> attn_b (stride 1024)
// blocks [1024,1280): retrieval (gather + q_g @ gdn, gate-scaled) -> retr_b
__global__ __launch_bounds__(256) void attn_retr(const bf16_t* __restrict__ qb,
                                                 const bf16_t* __restrict__ kb,
                                                 const bf16_t* __restrict__ vb,
                                                 const bf16_t* __restrict__ qgb,
                                                 const int* __restrict__ ids,
                                                 const float* __restrict__ bank,
                                                 const float* __restrict__ gdn,
                                                 const float* __restrict__ gm,
                                                 bf16_t* __restrict__ attn_b,
                                                 bf16_t* __restrict__ retr_b) {
  __shared__ alignas(16) char smem[35840];
  int tid = threadIdx.x;
  if (blockIdx.x < 1024) {
    bf16_t* Ks = (bf16_t*)smem;                    //  9216 B
    bf16_t* Vt = (bf16_t*)(smem + 9216);           //  9216 B
    float*  Oa = (float*)(smem + 18432);           // 17408 B
    int blk = blockIdx.x;
    int tcb = blk & 31;
    int h = (blk >> 5) & 15;
    int b = blk >> 9;
    int t0 = tcb * 64;
    int wv = tid >> 6, lane = tid & 63;
    int l15 = lane & 15, quad = lane >> 4;
    int tq0 = t0 + wv * 16;
    int t = tq0 + l15;
    int lo = t - 256; if (lo < 0) lo = 0;

    const bf16_t* qptr = qb + (((size_t)(b * 2048 + t) * 16) + h) * 64;
    bf16x8 qf0 = *(const bf16x8*)(qptr + quad * 8);
    bf16x8 qf1 = *(const bf16x8*)(qptr + 32 + quad * 8);

    f32x4 acc[4] = {};
    float mrun = -1e30f, lrun = 0.f;

    for (int c = 0; c < 5; ++c) {
      int s0 = t0 - 256 + c * 64;
      __syncthreads();
      #pragma unroll
      for (int it = 0; it < 2; ++it) {
        int task = tid + it * 256;
        int key = task >> 3, dseg = task & 7;
        int s = s0 + key; s = s < 0 ? 0 : (s > 2047 ? 2047 : s);
        *(bf16x8*)&Ks[key * 72 + dseg * 8] =
          *(const bf16x8*)(kb + (((size_t)(b * 2048 + s) * 16) + h) * 64 + dseg * 8);
      }
      {
        int vseg = tid & 7, kp = tid >> 3;
        int sA = s0 + 2 * kp, sB = sA + 1;
        sA = sA < 0 ? 0 : (sA > 2047 ? 2047 : sA);
        sB = sB < 0 ? 0 : (sB > 2047 ? 2047 : sB);
        bf16x8 va = *(const bf16x8*)(vb + (((size_t)(b * 2048 + sA) * 16) + h) * 64 + vseg * 8);
        bf16x8 vbv = *(const bf16x8*)(vb + (((size_t)(b * 2048 + sB) * 16) + h) * 64 + vseg * 8);
        #pragma unroll
        for (int j = 0; j < 8; ++j) {
          union { bf16_t h2[2]; unsigned int u; } pk;
          pk.h2[0] = va[j]; pk.h2[1] = vbv[j];
          *(unsigned int*)&Vt[(vseg * 8 + j) * 72 + 2 * kp] = pk.u;
        }
      }
      __syncthreads();
      #pragma unroll
      for (int p = 0; p < 2; ++p) {
        int sbase = s0 + p * 32;
        if (sbase > tq0 + 15 || sbase + 31 < tq0 - 256 || sbase + 31 < 0) continue;
        int kl = p * 32;
        bf16x8 ka0  = *(const bf16x8*)&Ks[(kl + l15) * 72 + quad * 8];
        bf16x8 ka0b = *(const bf16x8*)&Ks[(kl + l15) * 72 + 32 + quad * 8];
        bf16x8 ka1  = *(const bf16x8*)&Ks[(kl + 16 + l15) * 72 + quad * 8];
        bf16x8 ka1b = *(const bf16x8*)&Ks[(kl + 16 + l15) * 72 + 32 + quad * 8];
        f32x4 c0 = {}, c1 = {};
        c0 = __builtin_amdgcn_mfma_f32_16x16x32_bf16(ka0,  qf0, c0, 0, 0, 0);
        c0 = __builtin_amdgcn_mfma_f32_16x16x32_bf16(ka0b, qf1, c0, 0, 0, 0);
        c1 = __builtin_amdgcn_mfma_f32_16x16x32_bf16(ka1,  qf0, c1, 0, 0, 0);
        c1 = __builtin_amdgcn_mfma_f32_16x16x32_bf16(ka1b, qf1, c1, 0, 0, 0);
        float p0[4], p1[4];
        float mx = -1e30f;
        #pragma unroll
        for (int r = 0; r < 4; ++r) {
          int sK0 = sbase + quad * 4 + r;
          int sK1 = sK0 + 16;
          float v0 = (sK0 >= lo && sK0 <= t) ? c0[r] * 0.125f : -1e30f;
          float v1 = (sK1 >= lo && sK1 <= t) ? c1[r] * 0.125f : -1e30f;
          p0[r] = v0; p1[r] = v1;
          mx = fmaxf(mx, fmaxf(v0, v1));
        }
        mx = fmaxf(mx, __shfl_xor(mx, 16));
        mx = fmaxf(mx, __shfl_xor(mx, 32));
        float mnew = fmaxf(mrun, mx);
        float alpha = __expf(mrun - mnew);
        float rs = 0.f;
        #pragma unroll
        for (int r = 0; r < 4; ++r) {
          float e0 = (p0[r] > -1e29f) ? __expf(p0[r] - mnew) : 0.f;
          float e1 = (p1[r] > -1e29f) ? __expf(p1[r] - mnew) : 0.f;
          p0[r] = e0; p1[r] = e1;
          rs += e0 + e1;
        }
        rs += __shfl_xor(rs, 16);
        rs += __shfl_xor(rs, 32);
        mrun = mnew;
        lrun = lrun * alpha + rs;
        #pragma unroll
        for (int vt = 0; vt < 4; ++vt)
          #pragma unroll
          for (int r = 0; r < 4; ++r) acc[vt][r] *= alpha;
        union { bf16x4 v; int2 i2; } pka, pkb;
        #pragma unroll
        for (int r = 0; r < 4; ++r) { pka.v[r] = (bf16_t)p0[r]; pkb.v[r] = (bf16_t)p1[r]; }
        int sel = quad >> 1;
        int base = l15 + ((quad & 1) << 5);
        int a0 = __shfl(pka.i2.x, base),      b0 = __shfl(pkb.i2.x, base);
        int a1 = __shfl(pka.i2.y, base),      b1 = __shfl(pkb.i2.y, base);
        int a2 = __shfl(pka.i2.x, base + 16), b2 = __shfl(pkb.i2.x, base + 16);
        int a3 = __shfl(pka.i2.y, base + 16), b3 = __shfl(pkb.i2.y, base + 16);
        union { int4 i4; bf16x8 v; } pf;
        pf.i4.x = sel ? b0 : a0;
        pf.i4.y = sel ? b1 : a1;
        pf.i4.z = sel ? b2 : a2;
        pf.i4.w = sel ? b3 : a3;
        #pragma unroll
        for (int vt = 0; vt < 4; ++vt) {
          bf16x8 vfr = *(const bf16x8*)&Vt[(vt * 16 + l15) * 72 + kl + quad * 8];
          acc[vt] = __builtin_amdgcn_mfma_f32_16x16x32_bf16(vfr, pf.v, acc[vt], 0, 0, 0);
        }
      }
    }
    float rl = 1.0f / lrun;
    float* myOs = Oa + wv * (16 * 68);
    #pragma unroll
    for (int vt = 0; vt < 4; ++vt)
      #pragma unroll
      for (int r = 0; r < 4; ++r)
        myOs[l15 * 68 + vt * 16 + quad * 4 + r] = acc[vt][r] * rl;
    __syncthreads();
    #pragma unroll
    for (int q = 0; q < 16; ++q) {
      float v = myOs[q * 68 + lane];
      attn_b[(size_t)(b * 2048 + tq0 + q) * 1024 + h * 64 + lane] = (bf16_t)v;
    }
  } else {
    float* G = (float*)smem;                       // 16384 B
    int blk = blockIdx.x - 1024;     // 256 = 2*16*8
    int tc = blk & 7;
    int h = (blk >> 3) & 15;
    int b = blk >> 7;
    const f32x4* gsrc = (const f32x4*)(gdn + (size_t)(b * 16 + h) * 4096);
    #pragma unroll
    for (int it = 0; it < 4; ++it)
      ((f32x4*)G)[tid + it * 256] = gsrc[tid + it * 256];
    __syncthreads();
    int t = tc * 256 + tid;
    int id = ids[b * 2048 + t] - 50250;
    bool valid = (id >= 0) && (id < 64);
    const bf16_t* qrow = qgb + (((size_t)(b * 2048 + t) * 16) + h) * 64;
    const float* krow = bank + (size_t)(h * 64 + (valid ? id : 0)) * 64;
    float acc[64];
    #pragma unroll
    for (int v = 0; v < 64; ++v) acc[v] = 0.f;
    for (int k = 0; k < 64; ++k) {
      float qv = valid ? krow[k] : (float)qrow[k];
      const f32x4* gr = (const f32x4*)&G[k * 64];
      #pragma unroll
      for (int i = 0; i < 16; ++i) {
        f32x4 gv = gr[i];
        acc[i * 4 + 0] += qv * gv[0];
        acc[i * 4 + 1] += qv * gv[1];
        acc[i * 4 + 2] += qv * gv[2];
        acc[i * 4 + 3] += qv * gv[3];
      }
    }
    float g = gm[b * 2048 + t];
    bf16_t* orow = retr_b + (size_t)(b * 2048 + t) * 1024 + h * 64;
    #pragma unroll
    for (int i = 0; i < 8; ++i) {
      bf16x8 ov;
      #pragma unroll
      for (int j = 0; j < 8; ++j) ov[j] = (bf16_t)(acc[i * 8 + j] * g);
      *(bf16x8*)(orow + i * 8) = ov;
    }
  }
}

// ---------------------------------------------------------------------------
extern "C" void kernel_launch(void* const* d_in, const int* in_sizes, int n_in,
                              void* d_out, int out_size, void* d_ws, size_t ws_size,
                              hipStream_t stream) {
  const float* x        = (const float*)d_in[0];
  const float* gdn      = (const float*)d_in[1];
  const int*   ids      = (const int*)d_in[2];
  const float* key_bank = (const float*)d_in[3];
  const float* norm_w   = (const float*)d_in[4];
  const float* wq       = (const float*)d_in[5];
  const float* wk       = (const float*)d_in[6];
  const float* wv       = (const float*)d_in[7];
  const float* wo       = (const float*)d_in[8];
  const float* w_gq     = (const float*)d_in[9];
  const float* w_ro     = (const float*)d_in[10];
  const float* w_gate   = (const float*)d_in[11];
  const float* b_gate   = (const float*)d_in[12];

  char* p = (char*)d_ws;
  auto alloc = [&](size_t bytes) { char* r = p; p += (bytes + 255) & ~(size_t)255; return r; };
  const size_t ACT = (size_t)4096 * 1024 * 2;   // bf16 activation (8.4 MB)
  const size_t WTB = (size_t)1024 * 1024 * 2;   // bf16 weight (2.1 MB)
  bf16_t* xn_b   = (bf16_t*)alloc(ACT);
  bf16_t* wq_b   = (bf16_t*)alloc(WTB);
  bf16_t* wk_b   = (bf16_t*)alloc(WTB);
  bf16_t* wv_b   = (bf16_t*)alloc(WTB);
  bf16_t* wgq_b  = (bf16_t*)alloc(WTB);
  bf16_t* wo_b   = (bf16_t*)alloc(WTB);         // pre-scaled by 0.3
  bf16_t* wro_b  = (bf16_t*)alloc(WTB);
  bf16_t* qb     = (bf16_t*)alloc(ACT);
  bf16_t* kb     = (bf16_t*)alloc(ACT);
  bf16_t* vb     = (bf16_t*)alloc(ACT);
  bf16_t* qgb    = (bf16_t*)alloc(ACT);
  bf16_t* attn_b = (bf16_t*)alloc(ACT);
  bf16_t* retr_b = (bf16_t*)alloc(ACT);
  float*  gmean  = (float*)alloc(4096 * 4);
  float2* rtab   = (float2*)alloc(2048 * 32 * sizeof(float2));

  CvtArgs ca;
  ca.s[0] = wq;   ca.d[0] = wq_b;   ca.scale[0] = 1.0f;
  ca.s[1] = wk;   ca.d[1] = wk_b;   ca.scale[1] = 1.0f;
  ca.s[2] = wv;   ca.d[2] = wv_b;   ca.scale[2] = 1.0f;
  ca.s[3] = w_gq; ca.d[3] = wgq_b;  ca.scale[3] = 1.0f;
  ca.s[4] = wo;   ca.d[4] = wo_b;   ca.scale[4] = 0.3f;
  ca.s[5] = w_ro; ca.d[5] = wro_b;  ca.scale[5] = 1.0f;
  prep_kernel<<<10496, 256, 0, stream>>>(ca, x, norm_w, w_gate, b_gate,
                                         xn_b, gmean, rtab, (float*)d_out);

  // q(rope), k(rope), v, q_g in one dispatch; BK=64 (32 MFMA per barrier)
  GemmCfg g4;
  g4.seg[0] = {xn_b, wq_b,  (void*)qb,  1, 0};
  g4.seg[1] = {xn_b, wk_b,  (void*)kb,  1, 0};
  g4.seg[2] = {xn_b, wv_b,  (void*)vb,  0, 0};
  g4.seg[3] = {xn_b, wgq_b, (void*)qgb, 0, 0};
  g4.rope = rtab;
  gemm_bt<1024, 1024, 64><<<dim3(32, 32), 256, 0, stream>>>(g4);

  attn_retr<<<1280, 256, 0, stream>>>(qb, kb, vb, qgb, ids, key_bank, gdn,
                                      gmean, attn_b, retr_b);

  // tail: d_out (pre-init x) += attn@0.3wo^T + (g*retr)@wro^T, split-K x2
  // -> 1024 blocks (4/CU), partials merged by fp32 atomic add.
  GemmCfg gf;
  gf.seg[0] = {attn_b, wo_b,  d_out, 3, 0};
  gf.seg[1] = {attn_b, wo_b,  d_out, 3, 512};
  gf.seg[2] = {retr_b, wro_b, d_out, 3, 0};
  gf.seg[3] = {retr_b, wro_b, d_out, 3, 512};
  gf.rope = nullptr;
  gemm_bt<1024, 512, 32><<<dim3(32, 32), 256, 0, stream>>>(gf);
}

// Round 9
// 269.762 us; speedup vs baseline: 1.0357x; 1.0357x over previous
//
#include <hip/hip_runtime.h>
#include <cstddef>

typedef __bf16 bf16_t;
typedef __bf16 bf16x8 __attribute__((ext_vector_type(8)));
typedef __bf16 bf16x4 __attribute__((ext_vector_type(4)));
typedef float  f32x4  __attribute__((ext_vector_type(4)));

// Problem constants: B=2, T=2048, D=1024, H=16, K=V=64, W=256
// ---------------------------------------------------------------------------
// PREP megakernel (1 launch, 10496 blocks x 256 thr):
//   blocks [0,6144)    : fp32->bf16 convert of 6 weight matrices (w/ scale)
//   blocks [6144,6400) : RoPE cos/sin table (2048 x 32 float2)
//   blocks [6400,10496): RMSNorm + bf16 cast + gate mean + d_out := x
struct CvtArgs { const float* s[6]; bf16_t* d[6]; float scale[6]; };
__global__ __launch_bounds__(256) void prep_kernel(CvtArgs ca,
                                                   const float* __restrict__ x,
                                                   const float* __restrict__ nw,
                                                   const float* __restrict__ wg,
                                                   const float* __restrict__ bg,
                                                   bf16_t* __restrict__ xn,
                                                   float* __restrict__ gm,
                                                   float2* __restrict__ rtab,
                                                   float* __restrict__ dout) {
  __shared__ float red[4];
  __shared__ float gred[4][16];
  int bid = blockIdx.x;
  int tid = threadIdx.x;
  if (bid < 6144) {
    int m = bid >> 10;
    int i = (bid & 1023) * 256 + tid;        // 262144 f32x4 per matrix
    f32x4 v = ((const f32x4*)ca.s[m])[i];
    float sc = ca.scale[m];
    bf16x4 o;
    #pragma unroll
    for (int j = 0; j < 4; ++j) o[j] = (bf16_t)(v[j] * sc);
    *(bf16x4*)(ca.d[m] + (size_t)i * 4) = o;
    return;
  }
  if (bid < 6400) {
    int i = (bid - 6144) * 256 + tid;        // 65536 = 2048*32
    int t = i >> 5, d = i & 31;
    float inv = exp2f((float)d * -0.41524101186092029f);  // 10000^(-d/32)
    float sn, cs;
    sincosf((float)t * inv, &sn, &cs);
    rtab[i] = make_float2(cs, sn);
    return;
  }
  int t = bid - 6400;                        // 4096 token rows
  int wave = tid >> 6, lane = tid & 63;
  f32x4 v = ((const f32x4*)(x + (size_t)t * 1024))[tid];
  ((f32x4*)(dout + (size_t)t * 1024))[tid] = v;   // residual pre-init
  float ss = v[0]*v[0] + v[1]*v[1] + v[2]*v[2] + v[3]*v[3];
  #pragma unroll
  for (int off = 32; off >= 1; off >>= 1) ss += __shfl_xor(ss, off);
  if (lane == 0) red[wave] = ss;
  __syncthreads();
  float tot = red[0] + red[1] + red[2] + red[3];
  float rinv = rsqrtf(tot * (1.0f / 1024.0f) + 1e-6f);
  f32x4 wv = ((const f32x4*)nw)[tid];
  float xnv[4];
  bf16x4 o;
  #pragma unroll
  for (int i = 0; i < 4; ++i) { xnv[i] = v[i] * rinv * wv[i]; o[i] = (bf16_t)xnv[i]; }
  *(bf16x4*)(xn + (size_t)t * 1024 + tid * 4) = o;
  float ga[16];
  #pragma unroll
  for (int h = 0; h < 16; ++h) {
    f32x4 wgh = ((const f32x4*)(wg + h * 1024))[tid];
    ga[h] = xnv[0]*wgh[0] + xnv[1]*wgh[1] + xnv[2]*wgh[2] + xnv[3]*wgh[3];
  }
  #pragma unroll
  for (int h = 0; h < 16; ++h) {
    #pragma unroll
    for (int off = 32; off >= 1; off >>= 1) ga[h] += __shfl_xor(ga[h], off);
  }
  if (lane < 16) gred[wave][lane] = ga[lane];
  __syncthreads();
  if (tid < 16) {
    float s = gred[0][tid] + gred[1][tid] + gred[2][tid] + gred[3][tid];
    float sig = 1.0f / (1.0f + __expf(-(s + bg[tid])));
    #pragma unroll
    for (int off = 8; off >= 1; off >>= 1) sig += __shfl_xor(sig, off);
    if (tid == 0) gm[t] = sig * (1.0f / 16.0f);
  }
}

// ---------------------------------------------------------------------------
// bf16 MFMA GEMM, C = A (M x KD) * W^T, W row-major (1024 x KD).
// 128 x TN tile (TN=128: R7-proven g4 shape; TN=64: tail shape for 2x block
// count at identical atomic-write traffic). 4 waves, 16x16x32 MFMA, BK=32,
// padded LDS (LDSK=40, 2-way bank aliasing free).
// Runtime per-seg mode: 0 = bf16 out; 1 = bf16 + RoPE table; 3 = atomic fp32.
struct GemmSeg { const bf16_t* a; const bf16_t* w; void* c; int mode; };
struct GemmCfg { GemmSeg seg[4]; const float2* rope; };
#define LDSK 40
template<int KD, int TN>
__global__ __launch_bounds__(256, 2) void gemm_bt(GemmCfg cfg) {
  constexpr int NT = 1024 / TN;             // n-tiles per matrix
  constexpr int JN = TN / 32;               // j-tiles (16 col) per wave
  __shared__ bf16_t As[128 * LDSK];
  __shared__ bf16_t Bs[TN * LDSK];
  int seg = blockIdx.x / NT;
  const bf16_t* __restrict__ A = cfg.seg[seg].a;
  const bf16_t* __restrict__ W = cfg.seg[seg].w;
  int m0 = blockIdx.y * 128;
  int n0 = (blockIdx.x % NT) * TN;
  int tid = threadIdx.x;
  int lane = tid & 63, wave = tid >> 6;
  int wm = (wave >> 1) * 64, wn = (wave & 1) * (JN * 16);
  int l16 = lane & 15, quad = lane >> 4;
  f32x4 acc[4][JN] = {};
  for (int k0 = 0; k0 < KD; k0 += 32) {
    __syncthreads();
    #pragma unroll
    for (int c = 0; c < 2; ++c) {           // A: 512 16B chunks
      int ci = tid + c * 256;
      int r = ci >> 2;
      int ko = (ci & 3) * 8;
      *(uint4*)&As[r * LDSK + ko] = *(const uint4*)&A[(size_t)(m0 + r) * KD + k0 + ko];
    }
    #pragma unroll
    for (int c = 0; c < TN / 64; ++c) {     // B: TN*4 16B chunks
      int ci = tid + c * 256;
      int r = ci >> 2;
      int ko = (ci & 3) * 8;
      *(uint4*)&Bs[r * LDSK + ko] = *(const uint4*)&W[(size_t)(n0 + r) * KD + k0 + ko];
    }
    __syncthreads();
    bf16x8 af[4], bfr[JN];
    #pragma unroll
    for (int i = 0; i < 4; ++i)
      af[i]  = *(const bf16x8*)&As[(wm + i * 16 + l16) * LDSK + quad * 8];
    #pragma unroll
    for (int j = 0; j < JN; ++j)
      bfr[j] = *(const bf16x8*)&Bs[(wn + j * 16 + l16) * LDSK + quad * 8];
    #pragma unroll
    for (int i = 0; i < 4; ++i)
      #pragma unroll
      for (int j = 0; j < JN; ++j)
        acc[i][j] = __builtin_amdgcn_mfma_f32_16x16x32_bf16(af[i], bfr[j], acc[i][j], 0, 0, 0);
  }
  int mode = cfg.seg[seg].mode;
  // C/D layout: col = lane&15, row = quad*4 + reg
  if constexpr (TN == 128) {
    if (mode == 1) {
      const float2* tab = cfg.rope;
      #pragma unroll
      for (int jp = 0; jp < 2; ++jp) {
        int d = jp * 16 + l16;
        #pragma unroll
        for (int i = 0; i < 4; ++i)
          #pragma unroll
          for (int r = 0; r < 4; ++r) {
            int tseq = (m0 + wm + i * 16 + quad * 4 + r) & 2047;
            float2 cz = tab[(tseq << 5) + d];
            float v1 = acc[i][jp][r], v2 = acc[i][jp + 2][r];
            acc[i][jp][r]     = v1 * cz.x - v2 * cz.y;
            acc[i][jp + 2][r] = v2 * cz.x + v1 * cz.y;
          }
      }
    }
  }
  if (mode == 3) {
    float* C = (float*)cfg.seg[seg].c;
    #pragma unroll
    for (int i = 0; i < 4; ++i)
      #pragma unroll
      for (int j = 0; j < JN; ++j) {
        int row = m0 + wm + i * 16 + quad * 4;
        int col = n0 + wn + j * 16 + l16;
        #pragma unroll
        for (int r = 0; r < 4; ++r)
          unsafeAtomicAdd(&C[(size_t)(row + r) * 1024 + col], acc[i][j][r]);
      }
  } else {
    bf16_t* C = (bf16_t*)cfg.seg[seg].c;
    #pragma unroll
    for (int i = 0; i < 4; ++i)
      #pragma unroll
      for (int j = 0; j < JN; ++j) {
        int row = m0 + wm + i * 16 + quad * 4;
        int col = n0 + wn + j * 16 + l16;
        #pragma unroll
        for (int r = 0; r < 4; ++r)
          C[(size_t)(row + r) * 1024 + col] = (bf16_t)acc[i][j][r];
      }
  }
}

// ---------------------------------------------------------------------------
// Merged attention + retrieval (1 launch, 1280 blocks x 256 thr).
// blocks [0,1024): MFMA flash attention -> attn_b (stride 1024)
// blocks [1024,1280): retrieval (gather + q_g @ gdn, gate-scaled) -> retr_b
__global__ __launch_bounds__(256) void attn_retr(const bf16_t* __restrict__ qb,
                                                 const bf16_t* __restrict__ kb,
                                                 const bf16_t* __restrict__ vb,
                                                 const bf16_t* __restrict__ qgb,
                                                 const int* __restrict__ ids,
                                                 const float* __restrict__ bank,
                                                 const float* __restrict__ gdn,
                                                 const float* __restrict__ gm,
                                                 bf16_t* __restrict__ attn_b,
                                                 bf16_t* __restrict__ retr_b) {
  __shared__ alignas(16) char smem[35840];
  int tid = threadIdx.x;
  if (blockIdx.x < 1024) {
    bf16_t* Ks = (bf16_t*)smem;                    //  9216 B
    bf16_t* Vt = (bf16_t*)(smem + 9216);           //  9216 B
    float*  Oa = (float*)(smem + 18432);           // 17408 B
    int blk = blockIdx.x;
    int tcb = blk & 31;
    int h = (blk >> 5) & 15;
    int b = blk >> 9;
    int t0 = tcb * 64;
    int wv = tid >> 6, lane = tid & 63;
    int l15 = lane & 15, quad = lane >> 4;
    int tq0 = t0 + wv * 16;
    int t = tq0 + l15;
    int lo = t - 256; if (lo < 0) lo = 0;

    const bf16_t* qptr = qb + (((size_t)(b * 2048 + t) * 16) + h) * 64;
    bf16x8 qf0 = *(const bf16x8*)(qptr + quad * 8);
    bf16x8 qf1 = *(const bf16x8*)(qptr + 32 + quad * 8);

    f32x4 acc[4] = {};
    float mrun = -1e30f, lrun = 0.f;

    for (int c = 0; c < 5; ++c) {
      int s0 = t0 - 256 + c * 64;
      __syncthreads();
      #pragma unroll
      for (int it = 0; it < 2; ++it) {
        int task = tid + it * 256;
        int key = task >> 3, dseg = task & 7;
        int s = s0 + key; s = s < 0 ? 0 : (s > 2047 ? 2047 : s);
        *(bf16x8*)&Ks[key * 72 + dseg * 8] =
          *(const bf16x8*)(kb + (((size_t)(b * 2048 + s) * 16) + h) * 64 + dseg * 8);
      }
      {
        int vseg = tid & 7, kp = tid >> 3;
        int sA = s0 + 2 * kp, sB = sA + 1;
        sA = sA < 0 ? 0 : (sA > 2047 ? 2047 : sA);
        sB = sB < 0 ? 0 : (sB > 2047 ? 2047 : sB);
        bf16x8 va = *(const bf16x8*)(vb + (((size_t)(b * 2048 + sA) * 16) + h) * 64 + vseg * 8);
        bf16x8 vbv = *(const bf16x8*)(vb + (((size_t)(b * 2048 + sB) * 16) + h) * 64 + vseg * 8);
        #pragma unroll
        for (int j = 0; j < 8; ++j) {
          union { bf16_t h2[2]; unsigned int u; } pk;
          pk.h2[0] = va[j]; pk.h2[1] = vbv[j];
          *(unsigned int*)&Vt[(vseg * 8 + j) * 72 + 2 * kp] = pk.u;
        }
      }
      __syncthreads();
      #pragma unroll
      for (int p = 0; p < 2; ++p) {
        int sbase = s0 + p * 32;
        if (sbase > tq0 + 15 || sbase + 31 < tq0 - 256 || sbase + 31 < 0) continue;
        int kl = p * 32;
        bf16x8 ka0  = *(const bf16x8*)&Ks[(kl + l15) * 72 + quad * 8];
        bf16x8 ka0b = *(const bf16x8*)&Ks[(kl + l15) * 72 + 32 + quad * 8];
        bf16x8 ka1  = *(const bf16x8*)&Ks[(kl + 16 + l15) * 72 + quad * 8];
        bf16x8 ka1b = *(const bf16x8*)&Ks[(kl + 16 + l15) * 72 + 32 + quad * 8];
        f32x4 c0 = {}, c1 = {};
        c0 = __builtin_amdgcn_mfma_f32_16x16x32_bf16(ka0,  qf0, c0, 0, 0, 0);
        c0 = __builtin_amdgcn_mfma_f32_16x16x32_bf16(ka0b, qf1, c0, 0, 0, 0);
        c1 = __builtin_amdgcn_mfma_f32_16x16x32_bf16(ka1,  qf0, c1, 0, 0, 0);
        c1 = __builtin_amdgcn_mfma_f32_16x16x32_bf16(ka1b, qf1, c1, 0, 0, 0);
        float p0[4], p1[4];
        float mx = -1e30f;
        #pragma unroll
        for (int r = 0; r < 4; ++r) {
          int sK0 = sbase + quad * 4 + r;
          int sK1 = sK0 + 16;
          float v0 = (sK0 >= lo && sK0 <= t) ? c0[r] * 0.125f : -1e30f;
          float v1 = (sK1 >= lo && sK1 <= t) ? c1[r] * 0.125f : -1e30f;
          p0[r] = v0; p1[r] = v1;
          mx = fmaxf(mx, fmaxf(v0, v1));
        }
        mx = fmaxf(mx, __shfl_xor(mx, 16));
        mx = fmaxf(mx, __shfl_xor(mx, 32));
        float mnew = fmaxf(mrun, mx);
        float alpha = __expf(mrun - mnew);
        float rs = 0.f;
        #pragma unroll
        for (int r = 0; r < 4; ++r) {
          float e0 = (p0[r] > -1e29f) ? __expf(p0[r] - mnew) : 0.f;
          float e1 = (p1[r] > -1e29f) ? __expf(p1[r] - mnew) : 0.f;
          p0[r] = e0; p1[r] = e1;
          rs += e0 + e1;
        }
        rs += __shfl_xor(rs, 16);
        rs += __shfl_xor(rs, 32);
        mrun = mnew;
        lrun = lrun * alpha + rs;
        #pragma unroll
        for (int vt = 0; vt < 4; ++vt)
          #pragma unroll
          for (int r = 0; r < 4; ++r) acc[vt][r] *= alpha;
        union { bf16x4 v; int2 i2; } pka, pkb;
        #pragma unroll
        for (int r = 0; r < 4; ++r) { pka.v[r] = (bf16_t)p0[r]; pkb.v[r] = (bf16_t)p1[r]; }
        int sel = quad >> 1;
        int base = l15 + ((quad & 1) << 5);
        int a0 = __shfl(pka.i2.x, base),      b0 = __shfl(pkb.i2.x, base);
        int a1 = __shfl(pka.i2.y, base),      b1 = __shfl(pkb.i2.y, base);
        int a2 = __shfl(pka.i2.x, base + 16), b2 = __shfl(pkb.i2.x, base + 16);
        int a3 = __shfl(pka.i2.y, base + 16), b3 = __shfl(pkb.i2.y, base + 16);
        union { int4 i4; bf16x8 v; } pf;
        pf.i4.x = sel ? b0 : a0;
        pf.i4.y = sel ? b1 : a1;
        pf.i4.z = sel ? b2 : a2;
        pf.i4.w = sel ? b3 : a3;
        #pragma unroll
        for (int vt = 0; vt < 4; ++vt) {
          bf16x8 vfr = *(const bf16x8*)&Vt[(vt * 16 + l15) * 72 + kl + quad * 8];
          acc[vt] = __builtin_amdgcn_mfma_f32_16x16x32_bf16(vfr, pf.v, acc[vt], 0, 0, 0);
        }
      }
    }
    float rl = 1.0f / lrun;
    float* myOs = Oa + wv * (16 * 68);
    #pragma unroll
    for (int vt = 0; vt < 4; ++vt)
      #pragma unroll
      for (int r = 0; r < 4; ++r)
        myOs[l15 * 68 + vt * 16 + quad * 4 + r] = acc[vt][r] * rl;
    __syncthreads();
    #pragma unroll
    for (int q = 0; q < 16; ++q) {
      float v = myOs[q * 68 + lane];
      attn_b[(size_t)(b * 2048 + tq0 + q) * 1024 + h * 64 + lane] = (bf16_t)v;
    }
  } else {
    float* G = (float*)smem;                       // 16384 B
    int blk = blockIdx.x - 1024;     // 256 = 2*16*8
    int tc = blk & 7;
    int h = (blk >> 3) & 15;
    int b = blk >> 7;
    const f32x4* gsrc = (const f32x4*)(gdn + (size_t)(b * 16 + h) * 4096);
    #pragma unroll
    for (int it = 0; it < 4; ++it)
      ((f32x4*)G)[tid + it * 256] = gsrc[tid + it * 256];
    __syncthreads();
    int t = tc * 256 + tid;
    int id = ids[b * 2048 + t] - 50250;
    bool valid = (id >= 0) && (id < 64);
    const bf16_t* qrow = qgb + (((size_t)(b * 2048 + t) * 16) + h) * 64;
    const float* krow = bank + (size_t)(h * 64 + (valid ? id : 0)) * 64;
    float acc[64];
    #pragma unroll
    for (int v = 0; v < 64; ++v) acc[v] = 0.f;
    for (int k = 0; k < 64; ++k) {
      float qv = valid ? krow[k] : (float)qrow[k];
      const f32x4* gr = (const f32x4*)&G[k * 64];
      #pragma unroll
      for (int i = 0; i < 16; ++i) {
        f32x4 gv = gr[i];
        acc[i * 4 + 0] += qv * gv[0];
        acc[i * 4 + 1] += qv * gv[1];
        acc[i * 4 + 2] += qv * gv[2];
        acc[i * 4 + 3] += qv * gv[3];
      }
    }
    float g = gm[b * 2048 + t];
    bf16_t* orow = retr_b + (size_t)(b * 2048 + t) * 1024 + h * 64;
    #pragma unroll
    for (int i = 0; i < 8; ++i) {
      bf16x8 ov;
      #pragma unroll
      for (int j = 0; j < 8; ++j) ov[j] = (bf16_t)(acc[i * 8 + j] * g);
      *(bf16x8*)(orow + i * 8) = ov;
    }
  }
}

// ---------------------------------------------------------------------------
extern "C" void kernel_launch(void* const* d_in, const int* in_sizes, int n_in,
                              void* d_out, int out_size, void* d_ws, size_t ws_size,
                              hipStream_t stream) {
  const float* x        = (const float*)d_in[0];
  const float* gdn      = (const float*)d_in[1];
  const int*   ids      = (const int*)d_in[2];
  const float* key_bank = (const float*)d_in[3];
  const float* norm_w   = (const float*)d_in[4];
  const float* wq       = (const float*)d_in[5];
  const float* wk       = (const float*)d_in[6];
  const float* wv       = (const float*)d_in[7];
  const float* wo       = (const float*)d_in[8];
  const float* w_gq     = (const float*)d_in[9];
  const float* w_ro     = (const float*)d_in[10];
  const float* w_gate   = (const float*)d_in[11];
  const float* b_gate   = (const float*)d_in[12];

  char* p = (char*)d_ws;
  auto alloc = [&](size_t bytes) { char* r = p; p += (bytes + 255) & ~(size_t)255; return r; };
  const size_t ACT = (size_t)4096 * 1024 * 2;   // bf16 activation (8.4 MB)
  const size_t WTB = (size_t)1024 * 1024 * 2;   // bf16 weight (2.1 MB)
  bf16_t* xn_b   = (bf16_t*)alloc(ACT);
  bf16_t* wq_b   = (bf16_t*)alloc(WTB);
  bf16_t* wk_b   = (bf16_t*)alloc(WTB);
  bf16_t* wv_b   = (bf16_t*)alloc(WTB);
  bf16_t* wgq_b  = (bf16_t*)alloc(WTB);
  bf16_t* wo_b   = (bf16_t*)alloc(WTB);         // pre-scaled by 0.3
  bf16_t* wro_b  = (bf16_t*)alloc(WTB);
  bf16_t* qb     = (bf16_t*)alloc(ACT);
  bf16_t* kb     = (bf16_t*)alloc(ACT);
  bf16_t* vb     = (bf16_t*)alloc(ACT);
  bf16_t* qgb    = (bf16_t*)alloc(ACT);
  bf16_t* attn_b = (bf16_t*)alloc(ACT);
  bf16_t* retr_b = (bf16_t*)alloc(ACT);
  float*  gmean  = (float*)alloc(4096 * 4);
  float2* rtab   = (float2*)alloc(2048 * 32 * sizeof(float2));

  CvtArgs ca;
  ca.s[0] = wq;   ca.d[0] = wq_b;   ca.scale[0] = 1.0f;
  ca.s[1] = wk;   ca.d[1] = wk_b;   ca.scale[1] = 1.0f;
  ca.s[2] = wv;   ca.d[2] = wv_b;   ca.scale[2] = 1.0f;
  ca.s[3] = w_gq; ca.d[3] = wgq_b;  ca.scale[3] = 1.0f;
  ca.s[4] = wo;   ca.d[4] = wo_b;   ca.scale[4] = 0.3f;
  ca.s[5] = w_ro; ca.d[5] = wro_b;  ca.scale[5] = 1.0f;
  prep_kernel<<<10496, 256, 0, stream>>>(ca, x, norm_w, w_gate, b_gate,
                                         xn_b, gmean, rtab, (float*)d_out);

  // q(rope), k(rope), v, q_g in one dispatch (R7-proven: BK=32, TN=128)
  GemmCfg g4;
  g4.seg[0] = {xn_b, wq_b,  (void*)qb,  1};
  g4.seg[1] = {xn_b, wk_b,  (void*)kb,  1};
  g4.seg[2] = {xn_b, wv_b,  (void*)vb,  0};
  g4.seg[3] = {xn_b, wgq_b, (void*)qgb, 0};
  g4.rope = rtab;
  gemm_bt<1024, 128><<<dim3(32, 32), 256, 0, stream>>>(g4);

  attn_retr<<<1280, 256, 0, stream>>>(qb, kb, vb, qgb, ids, key_bank, gdn,
                                      gmean, attn_b, retr_b);

  // tail: d_out (pre-init x) += attn@0.3wo^T + (g*retr)@wro^T.
  // N-split: 128x64 tiles -> 2 segs x (32m x 16n) = 1024 blocks (4/CU),
  // same atomic count per output element as R7 (2 adds), unlike split-K.
  GemmCfg gf;
  gf.seg[0] = {attn_b, wo_b,  d_out, 3};
  gf.seg[1] = {retr_b, wro_b, d_out, 3};
  gf.seg[2] = gf.seg[0];
  gf.seg[3] = gf.seg[0];
  gf.rope = nullptr;
  gemm_bt<1024, 64><<<dim3(32, 32), 256, 0, stream>>>(gf);
}

// Round 10
// 262.022 us; speedup vs baseline: 1.0663x; 1.0295x over previous
//
#include <hip/hip_runtime.h>
#include <cstddef>

typedef __bf16 bf16_t;
typedef __bf16 bf16x8 __attribute__((ext_vector_type(8)));
typedef __bf16 bf16x4 __attribute__((ext_vector_type(4)));
typedef float  f32x4  __attribute__((ext_vector_type(4)));

// Problem constants: B=2, T=2048, D=1024, H=16, K=V=64, W=256
// ---------------------------------------------------------------------------
// PREP megakernel (1 launch, 10496 blocks x 256 thr):
//   blocks [0,6144)    : fp32->bf16 convert of 6 weight matrices (w/ scale)
//   blocks [6144,6400) : RoPE cos/sin table (2048 x 32 float2)
//   blocks [6400,10496): RMSNorm + bf16 cast + gate mean
struct CvtArgs { const float* s[6]; bf16_t* d[6]; float scale[6]; };
__global__ __launch_bounds__(256) void prep_kernel(CvtArgs ca,
                                                   const float* __restrict__ x,
                                                   const float* __restrict__ nw,
                                                   const float* __restrict__ wg,
                                                   const float* __restrict__ bg,
                                                   bf16_t* __restrict__ xn,
                                                   float* __restrict__ gm,
                                                   float2* __restrict__ rtab) {
  __shared__ float red[4];
  __shared__ float gred[4][16];
  int bid = blockIdx.x;
  int tid = threadIdx.x;
  if (bid < 6144) {
    int m = bid >> 10;
    int i = (bid & 1023) * 256 + tid;        // 262144 f32x4 per matrix
    f32x4 v = ((const f32x4*)ca.s[m])[i];
    float sc = ca.scale[m];
    bf16x4 o;
    #pragma unroll
    for (int j = 0; j < 4; ++j) o[j] = (bf16_t)(v[j] * sc);
    *(bf16x4*)(ca.d[m] + (size_t)i * 4) = o;
    return;
  }
  if (bid < 6400) {
    int i = (bid - 6144) * 256 + tid;        // 65536 = 2048*32
    int t = i >> 5, d = i & 31;
    float inv = exp2f((float)d * -0.41524101186092029f);  // 10000^(-d/32)
    float sn, cs;
    sincosf((float)t * inv, &sn, &cs);
    rtab[i] = make_float2(cs, sn);
    return;
  }
  int t = bid - 6400;                        // 4096 token rows
  int wave = tid >> 6, lane = tid & 63;
  f32x4 v = ((const f32x4*)(x + (size_t)t * 1024))[tid];
  float ss = v[0]*v[0] + v[1]*v[1] + v[2]*v[2] + v[3]*v[3];
  #pragma unroll
  for (int off = 32; off >= 1; off >>= 1) ss += __shfl_xor(ss, off);
  if (lane == 0) red[wave] = ss;
  __syncthreads();
  float tot = red[0] + red[1] + red[2] + red[3];
  float rinv = rsqrtf(tot * (1.0f / 1024.0f) + 1e-6f);
  f32x4 wv = ((const f32x4*)nw)[tid];
  float xnv[4];
  bf16x4 o;
  #pragma unroll
  for (int i = 0; i < 4; ++i) { xnv[i] = v[i] * rinv * wv[i]; o[i] = (bf16_t)xnv[i]; }
  *(bf16x4*)(xn + (size_t)t * 1024 + tid * 4) = o;
  float ga[16];
  #pragma unroll
  for (int h = 0; h < 16; ++h) {
    f32x4 wgh = ((const f32x4*)(wg + h * 1024))[tid];
    ga[h] = xnv[0]*wgh[0] + xnv[1]*wgh[1] + xnv[2]*wgh[2] + xnv[3]*wgh[3];
  }
  #pragma unroll
  for (int h = 0; h < 16; ++h) {
    #pragma unroll
    for (int off = 32; off >= 1; off >>= 1) ga[h] += __shfl_xor(ga[h], off);
  }
  if (lane < 16) gred[wave][lane] = ga[lane];
  __syncthreads();
  if (tid < 16) {
    float s = gred[0][tid] + gred[1][tid] + gred[2][tid] + gred[3][tid];
    float sig = 1.0f / (1.0f + __expf(-(s + bg[tid])));
    #pragma unroll
    for (int off = 8; off >= 1; off >>= 1) sig += __shfl_xor(sig, off);
    if (tid == 0) gm[t] = sig * (1.0f / 16.0f);
  }
}

// ---------------------------------------------------------------------------
// bf16 MFMA GEMM, C = sum_ph A_ph (M x 1024) * W_ph^T, W row-major.
// 128x128 tile, 4 waves x (4x4) 16x16x32 MFMA, BK=32, padded LDS (LDSK=40).
// SOFTWARE-PIPELINED: tile k+1 is prefetched into VGPRs after the LDS-ready
// barrier, so global-load latency overlaps ds_read+MFMA (the R1..R9 versions
// exposed it between the two barriers — MfmaUtil capped at ~26%).
// NPH accumulation phases (pointer pairs) per block => atomic-free K=2048.
// Epilogue modes: 0 = bf16 out; 1 = bf16 + RoPE table; 2 = fp32 out + X.
struct GemmSeg { const bf16_t* a; const bf16_t* w; void* c; int mode; };
struct GemmCfg { GemmSeg seg[4]; const float2* rope; const float* x; };
#define LDSK 40
template<int NPH>
__global__ __launch_bounds__(256, 2) void gemm_bt(GemmCfg cfg) {
  __shared__ bf16_t As[128 * LDSK];
  __shared__ bf16_t Bs[128 * LDSK];
  const GemmSeg* sp = &cfg.seg[(blockIdx.x >> 3) * NPH];
  int m0 = blockIdx.y * 128;
  int n0 = (blockIdx.x & 7) * 128;
  int tid = threadIdx.x;
  int lane = tid & 63, wave = tid >> 6;
  int wm = (wave >> 1) * 64, wn = (wave & 1) * 64;
  int l16 = lane & 15, quad = lane >> 4;
  // staging geometry (fixed per thread)
  int ci0 = tid, ci1 = tid + 256;
  int r0 = ci0 >> 2, k0o = (ci0 & 3) * 8;
  int r1 = ci1 >> 2, k1o = (ci1 & 3) * 8;
  uint4 pa0, pa1, pb0, pb1;
  auto prefetch = [&](const bf16_t* A_, const bf16_t* W_, int k0) {
    pa0 = *(const uint4*)&A_[(size_t)(m0 + r0) * 1024 + k0 + k0o];
    pa1 = *(const uint4*)&A_[(size_t)(m0 + r1) * 1024 + k0 + k1o];
    pb0 = *(const uint4*)&W_[(size_t)(n0 + r0) * 1024 + k0 + k0o];
    pb1 = *(const uint4*)&W_[(size_t)(n0 + r1) * 1024 + k0 + k1o];
  };
  f32x4 acc[4][4] = {};
  prefetch(sp[0].a, sp[0].w, 0);
  for (int kk = 0; kk < NPH * 1024; kk += 32) {
    __syncthreads();                 // all waves done reading prev LDS tile
    *(uint4*)&As[r0 * LDSK + k0o] = pa0;
    *(uint4*)&As[r1 * LDSK + k1o] = pa1;
    *(uint4*)&Bs[r0 * LDSK + k0o] = pb0;
    *(uint4*)&Bs[r1 * LDSK + k1o] = pb1;
    __syncthreads();                 // LDS tile ready
    int kn = kk + 32;
    if (kn < NPH * 1024)             // prefetch next tile: in flight during MFMA
      prefetch(sp[kn >> 10].a, sp[kn >> 10].w, kn & 1023);
    bf16x8 af[4], bfr[4];
    #pragma unroll
    for (int i = 0; i < 4; ++i) {
      af[i]  = *(const bf16x8*)&As[(wm + i * 16 + l16) * LDSK + quad * 8];
      bfr[i] = *(const bf16x8*)&Bs[(wn + i * 16 + l16) * LDSK + quad * 8];
    }
    #pragma unroll
    for (int i = 0; i < 4; ++i)
      #pragma unroll
      for (int j = 0; j < 4; ++j)
        acc[i][j] = __builtin_amdgcn_mfma_f32_16x16x32_bf16(af[i], bfr[j], acc[i][j], 0, 0, 0);
  }
  int mode = sp[0].mode;
  // C/D layout: col = lane&15, row = quad*4 + reg
  if (mode == 1) {
    const float2* tab = cfg.rope;
    #pragma unroll
    for (int jp = 0; jp < 2; ++jp) {
      int d = jp * 16 + l16;
      #pragma unroll
      for (int i = 0; i < 4; ++i)
        #pragma unroll
        for (int r = 0; r < 4; ++r) {
          int tseq = (m0 + wm + i * 16 + quad * 4 + r) & 2047;
          float2 cz = tab[(tseq << 5) + d];
          float v1 = acc[i][jp][r], v2 = acc[i][jp + 2][r];
          acc[i][jp][r]     = v1 * cz.x - v2 * cz.y;
          acc[i][jp + 2][r] = v2 * cz.x + v1 * cz.y;
        }
    }
  }
  if (mode == 2) {
    float* C = (float*)sp[0].c;
    const float* X = cfg.x;
    #pragma unroll
    for (int i = 0; i < 4; ++i)
      #pragma unroll
      for (int j = 0; j < 4; ++j) {
        int row = m0 + wm + i * 16 + quad * 4;
        int col = n0 + wn + j * 16 + l16;
        #pragma unroll
        for (int r = 0; r < 4; ++r) {
          size_t idx = (size_t)(row + r) * 1024 + col;
          C[idx] = X[idx] + acc[i][j][r];
        }
      }
  } else {
    bf16_t* C = (bf16_t*)sp[0].c;
    #pragma unroll
    for (int i = 0; i < 4; ++i)
      #pragma unroll
      for (int j = 0; j < 4; ++j) {
        int row = m0 + wm + i * 16 + quad * 4;
        int col = n0 + wn + j * 16 + l16;
        #pragma unroll
        for (int r = 0; r < 4; ++r)
          C[(size_t)(row + r) * 1024 + col] = (bf16_t)acc[i][j][r];
      }
  }
}

// ---------------------------------------------------------------------------
// Merged attention + retrieval (1 launch, 1280 blocks x 256 thr).
// blocks [0,1024): MFMA flash attention -> attn_b (stride 1024)
// blocks [1024,1280): retrieval (gather + q_g @ gdn, gate-scaled) -> retr_b
__global__ __launch_bounds__(256) void attn_retr(const bf16_t* __restrict__ qb,
                                                 const bf16_t* __restrict__ kb,
                                                 const bf16_t* __restrict__ vb,
                                                 const bf16_t* __restrict__ qgb,
                                                 const int* __restrict__ ids,
                                                 const float* __restrict__ bank,
                                                 const float* __restrict__ gdn,
                                                 const float* __restrict__ gm,
                                                 bf16_t* __restrict__ attn_b,
                                                 bf16_t* __restrict__ retr_b) {
  __shared__ alignas(16) char smem[35840];
  int tid = threadIdx.x;
  if (blockIdx.x < 1024) {
    bf16_t* Ks = (bf16_t*)smem;                    //  9216 B
    bf16_t* Vt = (bf16_t*)(smem + 9216);           //  9216 B
    float*  Oa = (float*)(smem + 18432);           // 17408 B
    int blk = blockIdx.x;
    int tcb = blk & 31;
    int h = (blk >> 5) & 15;
    int b = blk >> 9;
    int t0 = tcb * 64;
    int wv = tid >> 6, lane = tid & 63;
    int l15 = lane & 15, quad = lane >> 4;
    int tq0 = t0 + wv * 16;
    int t = tq0 + l15;
    int lo = t - 256; if (lo < 0) lo = 0;

    const bf16_t* qptr = qb + (((size_t)(b * 2048 + t) * 16) + h) * 64;
    bf16x8 qf0 = *(const bf16x8*)(qptr + quad * 8);
    bf16x8 qf1 = *(const bf16x8*)(qptr + 32 + quad * 8);

    f32x4 acc[4] = {};
    float mrun = -1e30f, lrun = 0.f;

    for (int c = 0; c < 5; ++c) {
      int s0 = t0 - 256 + c * 64;
      __syncthreads();
      #pragma unroll
      for (int it = 0; it < 2; ++it) {
        int task = tid + it * 256;
        int key = task >> 3, dseg = task & 7;
        int s = s0 + key; s = s < 0 ? 0 : (s > 2047 ? 2047 : s);
        *(bf16x8*)&Ks[key * 72 + dseg * 8] =
          *(const bf16x8*)(kb + (((size_t)(b * 2048 + s) * 16) + h) * 64 + dseg * 8);
      }
      {
        int vseg = tid & 7, kp = tid >> 3;
        int sA = s0 + 2 * kp, sB = sA + 1;
        sA = sA < 0 ? 0 : (sA > 2047 ? 2047 : sA);
        sB = sB < 0 ? 0 : (sB > 2047 ? 2047 : sB);
        bf16x8 va = *(const bf16x8*)(vb + (((size_t)(b * 2048 + sA) * 16) + h) * 64 + vseg * 8);
        bf16x8 vbv = *(const bf16x8*)(vb + (((size_t)(b * 2048 + sB) * 16) + h) * 64 + vseg * 8);
        #pragma unroll
        for (int j = 0; j < 8; ++j) {
          union { bf16_t h2[2]; unsigned int u; } pk;
          pk.h2[0] = va[j]; pk.h2[1] = vbv[j];
          *(unsigned int*)&Vt[(vseg * 8 + j) * 72 + 2 * kp] = pk.u;
        }
      }
      __syncthreads();
      #pragma unroll
      for (int p = 0; p < 2; ++p) {
        int sbase = s0 + p * 32;
        if (sbase > tq0 + 15 || sbase + 31 < tq0 - 256 || sbase + 31 < 0) continue;
        int kl = p * 32;
        bf16x8 ka0  = *(const bf16x8*)&Ks[(kl + l15) * 72 + quad * 8];
        bf16x8 ka0b = *(const bf16x8*)&Ks[(kl + l15) * 72 + 32 + quad * 8];
        bf16x8 ka1  = *(const bf16x8*)&Ks[(kl + 16 + l15) * 72 + quad * 8];
        bf16x8 ka1b = *(const bf16x8*)&Ks[(kl + 16 + l15) * 72 + 32 + quad * 8];
        f32x4 c0 = {}, c1 = {};
        c0 = __builtin_amdgcn_mfma_f32_16x16x32_bf16(ka0,  qf0, c0, 0, 0, 0);
        c0 = __builtin_amdgcn_mfma_f32_16x16x32_bf16(ka0b, qf1, c0, 0, 0, 0);
        c1 = __builtin_amdgcn_mfma_f32_16x16x32_bf16(ka1,  qf0, c1, 0, 0, 0);
        c1 = __builtin_amdgcn_mfma_f32_16x16x32_bf16(ka1b, qf1, c1, 0, 0, 0);
        float p0[4], p1[4];
        float mx = -1e30f;
        #pragma unroll
        for (int r = 0; r < 4; ++r) {
          int sK0 = sbase + quad * 4 + r;
          int sK1 = sK0 + 16;
          float v0 = (sK0 >= lo && sK0 <= t) ? c0[r] * 0.125f : -1e30f;
          float v1 = (sK1 >= lo && sK1 <= t) ? c1[r] * 0.125f : -1e30f;
          p0[r] = v0; p1[r] = v1;
          mx = fmaxf(mx, fmaxf(v0, v1));
        }
        mx = fmaxf(mx, __shfl_xor(mx, 16));
        mx = fmaxf(mx, __shfl_xor(mx, 32));
        float mnew = fmaxf(mrun, mx);
        float alpha = __expf(mrun - mnew);
        float rs = 0.f;
        #pragma unroll
        for (int r = 0; r < 4; ++r) {
          float e0 = (p0[r] > -1e29f) ? __expf(p0[r] - mnew) : 0.f;
          float e1 = (p1[r] > -1e29f) ? __expf(p1[r] - mnew) : 0.f;
          p0[r] = e0; p1[r] = e1;
          rs += e0 + e1;
        }
        rs += __shfl_xor(rs, 16);
        rs += __shfl_xor(rs, 32);
        mrun = mnew;
        lrun = lrun * alpha + rs;
        #pragma unroll
        for (int vt = 0; vt < 4; ++vt)
          #pragma unroll
          for (int r = 0; r < 4; ++r) acc[vt][r] *= alpha;
        union { bf16x4 v; int2 i2; } pka, pkb;
        #pragma unroll
        for (int r = 0; r < 4; ++r) { pka.v[r] = (bf16_t)p0[r]; pkb.v[r] = (bf16_t)p1[r]; }
        int sel = quad >> 1;
        int base = l15 + ((quad & 1) << 5);
        int a0 = __shfl(pka.i2.x, base),      b0 = __shfl(pkb.i2.x, base);
        int a1 = __shfl(pka.i2.y, base),      b1 = __shfl(pkb.i2.y, base);
        int a2 = __shfl(pka.i2.x, base + 16), b2 = __shfl(pkb.i2.x, base + 16);
        int a3 = __shfl(pka.i2.y, base + 16), b3 = __shfl(pkb.i2.y, base + 16);
        union { int4 i4; bf16x8 v; } pf;
        pf.i4.x = sel ? b0 : a0;
        pf.i4.y = sel ? b1 : a1;
        pf.i4.z = sel ? b2 : a2;
        pf.i4.w = sel ? b3 : a3;
        #pragma unroll
        for (int vt = 0; vt < 4; ++vt) {
          bf16x8 vfr = *(const bf16x8*)&Vt[(vt * 16 + l15) * 72 + kl + quad * 8];
          acc[vt] = __builtin_amdgcn_mfma_f32_16x16x32_bf16(vfr, pf.v, acc[vt], 0, 0, 0);
        }
      }
    }
    float rl = 1.0f / lrun;
    float* myOs = Oa + wv * (16 * 68);
    #pragma unroll
    for (int vt = 0; vt < 4; ++vt)
      #pragma unroll
      for (int r = 0; r < 4; ++r)
        myOs[l15 * 68 + vt * 16 + quad * 4 + r] = acc[vt][r] * rl;
    __syncthreads();
    #pragma unroll
    for (int q = 0; q < 16; ++q) {
      float v = myOs[q * 68 + lane];
      attn_b[(size_t)(b * 2048 + tq0 + q) * 1024 + h * 64 + lane] = (bf16_t)v;
    }
  } else {
    float* G = (float*)smem;                       // 16384 B
    int blk = blockIdx.x - 1024;     // 256 = 2*16*8
    int tc = blk & 7;
    int h = (blk >> 3) & 15;
    int b = blk >> 7;
    const f32x4* gsrc = (const f32x4*)(gdn + (size_t)(b * 16 + h) * 4096);
    #pragma unroll
    for (int it = 0; it < 4; ++it)
      ((f32x4*)G)[tid + it * 256] = gsrc[tid + it * 256];
    __syncthreads();
    int t = tc * 256 + tid;
    int id = ids[b * 2048 + t] - 50250;
    bool valid = (id >= 0) && (id < 64);
    const bf16_t* qrow = qgb + (((size_t)(b * 2048 + t) * 16) + h) * 64;
    const float* krow = bank + (size_t)(h * 64 + (valid ? id : 0)) * 64;
    float acc[64];
    #pragma unroll
    for (int v = 0; v < 64; ++v) acc[v] = 0.f;
    for (int k = 0; k < 64; ++k) {
      float qv = valid ? krow[k] : (float)qrow[k];
      const f32x4* gr = (const f32x4*)&G[k * 64];
      #pragma unroll
      for (int i = 0; i < 16; ++i) {
        f32x4 gv = gr[i];
        acc[i * 4 + 0] += qv * gv[0];
        acc[i * 4 + 1] += qv * gv[1];
        acc[i * 4 + 2] += qv * gv[2];
        acc[i * 4 + 3] += qv * gv[3];
      }
    }
    float g = gm[b * 2048 + t];
    bf16_t* orow = retr_b + (size_t)(b * 2048 + t) * 1024 + h * 64;
    #pragma unroll
    for (int i = 0; i < 8; ++i) {
      bf16x8 ov;
      #pragma unroll
      for (int j = 0; j < 8; ++j) ov[j] = (bf16_t)(acc[i * 8 + j] * g);
      *(bf16x8*)(orow + i * 8) = ov;
    }
  }
}

// ---------------------------------------------------------------------------
extern "C" void kernel_launch(void* const* d_in, const int* in_sizes, int n_in,
                              void* d_out, int out_size, void* d_ws, size_t ws_size,
                              hipStream_t stream) {
  const float* x        = (const float*)d_in[0];
  const float* gdn      = (const float*)d_in[1];
  const int*   ids      = (const int*)d_in[2];
  const float* key_bank = (const float*)d_in[3];
  const float* norm_w   = (const float*)d_in[4];
  const float* wq       = (const float*)d_in[5];
  const float* wk       = (const float*)d_in[6];
  const float* wv       = (const float*)d_in[7];
  const float* wo       = (const float*)d_in[8];
  const float* w_gq     = (const float*)d_in[9];
  const float* w_ro     = (const float*)d_in[10];
  const float* w_gate   = (const float*)d_in[11];
  const float* b_gate   = (const float*)d_in[12];

  char* p = (char*)d_ws;
  auto alloc = [&](size_t bytes) { char* r = p; p += (bytes + 255) & ~(size_t)255; return r; };
  const size_t ACT = (size_t)4096 * 1024 * 2;   // bf16 activation (8.4 MB)
  const size_t WTB = (size_t)1024 * 1024 * 2;   // bf16 weight (2.1 MB)
  bf16_t* xn_b   = (bf16_t*)alloc(ACT);
  bf16_t* wq_b   = (bf16_t*)alloc(WTB);
  bf16_t* wk_b   = (bf16_t*)alloc(WTB);
  bf16_t* wv_b   = (bf16_t*)alloc(WTB);
  bf16_t* wgq_b  = (bf16_t*)alloc(WTB);
  bf16_t* wo_b   = (bf16_t*)alloc(WTB);         // pre-scaled by 0.3
  bf16_t* wro_b  = (bf16_t*)alloc(WTB);
  bf16_t* qb     = (bf16_t*)alloc(ACT);
  bf16_t* kb     = (bf16_t*)alloc(ACT);
  bf16_t* vb     = (bf16_t*)alloc(ACT);
  bf16_t* qgb    = (bf16_t*)alloc(ACT);
  bf16_t* attn_b = (bf16_t*)alloc(ACT);
  bf16_t* retr_b = (bf16_t*)alloc(ACT);
  float*  gmean  = (float*)alloc(4096 * 4);
  float2* rtab   = (float2*)alloc(2048 * 32 * sizeof(float2));

  CvtArgs ca;
  ca.s[0] = wq;   ca.d[0] = wq_b;   ca.scale[0] = 1.0f;
  ca.s[1] = wk;   ca.d[1] = wk_b;   ca.scale[1] = 1.0f;
  ca.s[2] = wv;   ca.d[2] = wv_b;   ca.scale[2] = 1.0f;
  ca.s[3] = w_gq; ca.d[3] = wgq_b;  ca.scale[3] = 1.0f;
  ca.s[4] = wo;   ca.d[4] = wo_b;   ca.scale[4] = 0.3f;
  ca.s[5] = w_ro; ca.d[5] = wro_b;  ca.scale[5] = 1.0f;
  prep_kernel<<<10496, 256, 0, stream>>>(ca, x, norm_w, w_gate, b_gate,
                                         xn_b, gmean, rtab);

  // q(rope), k(rope), v, q_g in one dispatch (pipelined K-loop)
  GemmCfg g4;
  g4.seg[0] = {xn_b, wq_b,  (void*)qb,  1};
  g4.seg[1] = {xn_b, wk_b,  (void*)kb,  1};
  g4.seg[2] = {xn_b, wv_b,  (void*)vb,  0};
  g4.seg[3] = {xn_b, wgq_b, (void*)qgb, 0};
  g4.rope = rtab;
  g4.x = nullptr;
  gemm_bt<1><<<dim3(32, 32), 256, 0, stream>>>(g4);

  attn_retr<<<1280, 256, 0, stream>>>(qb, kb, vb, qgb, ids, key_bank, gdn,
                                      gmean, attn_b, retr_b);

  // tail: d_out = x + attn@0.3wo^T + (g*retr)@wro^T in ONE accumulation
  // (2 phases, K=2048, single writer -> no atomics), 256 blocks.
  GemmCfg gf;
  gf.seg[0] = {attn_b, wo_b,  d_out, 2};
  gf.seg[1] = {retr_b, wro_b, d_out, 2};
  gf.rope = nullptr;
  gf.x = x;
  gemm_bt<2><<<dim3(8, 32), 256, 0, stream>>>(gf);
}

// Round 11
// 255.525 us; speedup vs baseline: 1.0934x; 1.0254x over previous
//
#include <hip/hip_runtime.h>
#include <cstddef>

typedef __bf16 bf16_t;
typedef __bf16 bf16x8 __attribute__((ext_vector_type(8)));
typedef __bf16 bf16x4 __attribute__((ext_vector_type(4)));
typedef float  f32x4  __attribute__((ext_vector_type(4)));

typedef const __attribute__((address_space(1))) void* gas_p;
typedef __attribute__((address_space(3))) void* las_p;
__device__ __forceinline__ void gload16(const bf16_t* g, bf16_t* l) {
  __builtin_amdgcn_global_load_lds((gas_p)g, (las_p)l, 16, 0, 0);
}

// Problem constants: B=2, T=2048, D=1024, H=16, K=V=64, W=256
// ---------------------------------------------------------------------------
// PREP megakernel (1 launch, 10496 blocks x 256 thr):
//   blocks [0,6144)    : fp32->bf16 convert of 6 weight matrices (w/ scale)
//   blocks [6144,6400) : RoPE cos/sin table (2048 x 32 float2)
//   blocks [6400,10496): RMSNorm + bf16 cast + gate mean
struct CvtArgs { const float* s[6]; bf16_t* d[6]; float scale[6]; };
__global__ __launch_bounds__(256) void prep_kernel(CvtArgs ca,
                                                   const float* __restrict__ x,
                                                   const float* __restrict__ nw,
                                                   const float* __restrict__ wg,
                                                   const float* __restrict__ bg,
                                                   bf16_t* __restrict__ xn,
                                                   float* __restrict__ gm,
                                                   float2* __restrict__ rtab) {
  __shared__ float red[4];
  __shared__ float gred[4][16];
  int bid = blockIdx.x;
  int tid = threadIdx.x;
  if (bid < 6144) {
    int m = bid >> 10;
    int i = (bid & 1023) * 256 + tid;        // 262144 f32x4 per matrix
    f32x4 v = ((const f32x4*)ca.s[m])[i];
    float sc = ca.scale[m];
    bf16x4 o;
    #pragma unroll
    for (int j = 0; j < 4; ++j) o[j] = (bf16_t)(v[j] * sc);
    *(bf16x4*)(ca.d[m] + (size_t)i * 4) = o;
    return;
  }
  if (bid < 6400) {
    int i = (bid - 6144) * 256 + tid;        // 65536 = 2048*32
    int t = i >> 5, d = i & 31;
    float inv = exp2f((float)d * -0.41524101186092029f);  // 10000^(-d/32)
    float sn, cs;
    sincosf((float)t * inv, &sn, &cs);
    rtab[i] = make_float2(cs, sn);
    return;
  }
  int t = bid - 6400;                        // 4096 token rows
  int wave = tid >> 6, lane = tid & 63;
  f32x4 v = ((const f32x4*)(x + (size_t)t * 1024))[tid];
  float ss = v[0]*v[0] + v[1]*v[1] + v[2]*v[2] + v[3]*v[3];
  #pragma unroll
  for (int off = 32; off >= 1; off >>= 1) ss += __shfl_xor(ss, off);
  if (lane == 0) red[wave] = ss;
  __syncthreads();
  float tot = red[0] + red[1] + red[2] + red[3];
  float rinv = rsqrtf(tot * (1.0f / 1024.0f) + 1e-6f);
  f32x4 wv = ((const f32x4*)nw)[tid];
  float xnv[4];
  bf16x4 o;
  #pragma unroll
  for (int i = 0; i < 4; ++i) { xnv[i] = v[i] * rinv * wv[i]; o[i] = (bf16_t)xnv[i]; }
  *(bf16x4*)(xn + (size_t)t * 1024 + tid * 4) = o;
  float ga[16];
  #pragma unroll
  for (int h = 0; h < 16; ++h) {
    f32x4 wgh = ((const f32x4*)(wg + h * 1024))[tid];
    ga[h] = xnv[0]*wgh[0] + xnv[1]*wgh[1] + xnv[2]*wgh[2] + xnv[3]*wgh[3];
  }
  #pragma unroll
  for (int h = 0; h < 16; ++h) {
    #pragma unroll
    for (int off = 32; off >= 1; off >>= 1) ga[h] += __shfl_xor(ga[h], off);
  }
  if (lane < 16) gred[wave][lane] = ga[lane];
  __syncthreads();
  if (tid < 16) {
    float s = gred[0][tid] + gred[1][tid] + gred[2][tid] + gred[3][tid];
    float sig = 1.0f / (1.0f + __expf(-(s + bg[tid])));
    #pragma unroll
    for (int off = 8; off >= 1; off >>= 1) sig += __shfl_xor(sig, off);
    if (tid == 0) gm[t] = sig * (1.0f / 16.0f);
  }
}

// ---------------------------------------------------------------------------
// g4 GEMM: m97 structure — global_load_lds width=16, unpadded 128x32 LDS
// tiles (16 KB total). KD=1024 compile-time. Each wave owns 32 tile rows;
// lane -> row wave*32+(lane>>2), elem (lane&3)*8; HW writes base+lane*16B
// which matches exactly (verified correct in R4). Runtime per-seg mode:
// 0 = bf16 out; 1 = bf16 + RoPE via table (no transcendentals -> low VGPR).
struct GemmSeg { const bf16_t* a; const bf16_t* w; void* c; int mode; };
struct GemmCfg { GemmSeg seg[4]; const float2* rope; const float* x; };
__global__ __launch_bounds__(256, 2) void gemm_glds(GemmCfg cfg) {
  __shared__ bf16_t As[128 * 32];
  __shared__ bf16_t Bs[128 * 32];
  int seg = blockIdx.x >> 3;
  const bf16_t* __restrict__ A = cfg.seg[seg].a;
  const bf16_t* __restrict__ W = cfg.seg[seg].w;
  int m0 = blockIdx.y * 128;
  int n0 = (blockIdx.x & 7) * 128;
  int tid = threadIdx.x;
  int lane = tid & 63, wave = tid >> 6;
  int wm = (wave >> 1) * 64, wn = (wave & 1) * 64;
  int l16 = lane & 15, quad = lane >> 4;
  const bf16_t* agp = A + (size_t)(m0 + wave * 32 + (lane >> 2)) * 1024 + (lane & 3) * 8;
  const bf16_t* wgp = W + (size_t)(n0 + wave * 32 + (lane >> 2)) * 1024 + (lane & 3) * 8;
  bf16_t* alds = &As[wave * 32 * 32];
  bf16_t* blds = &Bs[wave * 32 * 32];
  f32x4 acc[4][4] = {};
  for (int k0 = 0; k0 < 1024; k0 += 32) {
    __syncthreads();
    gload16(agp + k0,             alds);
    gload16(agp + k0 + 16 * 1024, alds + 16 * 32);
    gload16(wgp + k0,             blds);
    gload16(wgp + k0 + 16 * 1024, blds + 16 * 32);
    __syncthreads();
    bf16x8 af[4], bfr[4];
    #pragma unroll
    for (int i = 0; i < 4; ++i) {
      af[i]  = *(const bf16x8*)&As[(wm + i * 16 + l16) * 32 + quad * 8];
      bfr[i] = *(const bf16x8*)&Bs[(wn + i * 16 + l16) * 32 + quad * 8];
    }
    #pragma unroll
    for (int i = 0; i < 4; ++i)
      #pragma unroll
      for (int j = 0; j < 4; ++j)
        acc[i][j] = __builtin_amdgcn_mfma_f32_16x16x32_bf16(af[i], bfr[j], acc[i][j], 0, 0, 0);
  }
  int mode = cfg.seg[seg].mode;
  // C/D layout: col = lane&15, row = quad*4 + reg
  if (mode == 1) {
    const float2* tab = cfg.rope;
    #pragma unroll
    for (int jp = 0; jp < 2; ++jp) {
      int d = jp * 16 + l16;
      #pragma unroll
      for (int i = 0; i < 4; ++i)
        #pragma unroll
        for (int r = 0; r < 4; ++r) {
          int tseq = (m0 + wm + i * 16 + quad * 4 + r) & 2047;
          float2 cz = tab[(tseq << 5) + d];
          float v1 = acc[i][jp][r], v2 = acc[i][jp + 2][r];
          acc[i][jp][r]     = v1 * cz.x - v2 * cz.y;
          acc[i][jp + 2][r] = v2 * cz.x + v1 * cz.y;
        }
    }
  }
  bf16_t* C = (bf16_t*)cfg.seg[seg].c;
  #pragma unroll
  for (int i = 0; i < 4; ++i)
    #pragma unroll
    for (int j = 0; j < 4; ++j) {
      int row = m0 + wm + i * 16 + quad * 4;
      int col = n0 + wn + j * 16 + l16;
      #pragma unroll
      for (int r = 0; r < 4; ++r)
        C[(size_t)(row + r) * 1024 + col] = (bf16_t)acc[i][j][r];
    }
}

// ---------------------------------------------------------------------------
// Tail GEMM: R10-proven pipelined VGPR staging (right structure for the
// 256-block 1/CU grid), NPH accumulation phases (atomic-free K=2048),
// epilogue d_out = X + acc (fp32).
#define LDSK 40
template<int NPH>
__global__ __launch_bounds__(256, 2) void gemm_pipe(GemmCfg cfg) {
  __shared__ bf16_t As[128 * LDSK];
  __shared__ bf16_t Bs[128 * LDSK];
  const GemmSeg* sp = &cfg.seg[(blockIdx.x >> 3) * NPH];
  int m0 = blockIdx.y * 128;
  int n0 = (blockIdx.x & 7) * 128;
  int tid = threadIdx.x;
  int lane = tid & 63, wave = tid >> 6;
  int wm = (wave >> 1) * 64, wn = (wave & 1) * 64;
  int l16 = lane & 15, quad = lane >> 4;
  int ci0 = tid, ci1 = tid + 256;
  int r0 = ci0 >> 2, k0o = (ci0 & 3) * 8;
  int r1 = ci1 >> 2, k1o = (ci1 & 3) * 8;
  uint4 pa0, pa1, pb0, pb1;
  auto prefetch = [&](const bf16_t* A_, const bf16_t* W_, int k0) {
    pa0 = *(const uint4*)&A_[(size_t)(m0 + r0) * 1024 + k0 + k0o];
    pa1 = *(const uint4*)&A_[(size_t)(m0 + r1) * 1024 + k0 + k1o];
    pb0 = *(const uint4*)&W_[(size_t)(n0 + r0) * 1024 + k0 + k0o];
    pb1 = *(const uint4*)&W_[(size_t)(n0 + r1) * 1024 + k0 + k1o];
  };
  f32x4 acc[4][4] = {};
  prefetch(sp[0].a, sp[0].w, 0);
  for (int kk = 0; kk < NPH * 1024; kk += 32) {
    __syncthreads();
    *(uint4*)&As[r0 * LDSK + k0o] = pa0;
    *(uint4*)&As[r1 * LDSK + k1o] = pa1;
    *(uint4*)&Bs[r0 * LDSK + k0o] = pb0;
    *(uint4*)&Bs[r1 * LDSK + k1o] = pb1;
    __syncthreads();
    int kn = kk + 32;
    if (kn < NPH * 1024)
      prefetch(sp[kn >> 10].a, sp[kn >> 10].w, kn & 1023);
    bf16x8 af[4], bfr[4];
    #pragma unroll
    for (int i = 0; i < 4; ++i) {
      af[i]  = *(const bf16x8*)&As[(wm + i * 16 + l16) * LDSK + quad * 8];
      bfr[i] = *(const bf16x8*)&Bs[(wn + i * 16 + l16) * LDSK + quad * 8];
    }
    #pragma unroll
    for (int i = 0; i < 4; ++i)
      #pragma unroll
      for (int j = 0; j < 4; ++j)
        acc[i][j] = __builtin_amdgcn_mfma_f32_16x16x32_bf16(af[i], bfr[j], acc[i][j], 0, 0, 0);
  }
  float* C = (float*)sp[0].c;
  const float* X = cfg.x;
  #pragma unroll
  for (int i = 0; i < 4; ++i)
    #pragma unroll
    for (int j = 0; j < 4; ++j) {
      int row = m0 + wm + i * 16 + quad * 4;
      int col = n0 + wn + j * 16 + l16;
      #pragma unroll
      for (int r = 0; r < 4; ++r) {
        size_t idx = (size_t)(row + r) * 1024 + col;
        C[idx] = X[idx] + acc[i][j][r];
      }
    }
}

// ---------------------------------------------------------------------------
// Merged attention + retrieval (1 launch, 1280 blocks x 256 thr).
// blocks [0,1024): MFMA flash attention -> attn_b (stride 1024)
// blocks [1024,1280): retrieval (gather + q_g @ gdn, gate-scaled) -> retr_b
__global__ __launch_bounds__(256) void attn_retr(const bf16_t* __restrict__ qb,
                                                 const bf16_t* __restrict__ kb,
                                                 const bf16_t* __restrict__ vb,
                                                 const bf16_t* __restrict__ qgb,
                                                 const int* __restrict__ ids,
                                                 const float* __restrict__ bank,
                                                 const float* __restrict__ gdn,
                                                 const float* __restrict__ gm,
                                                 bf16_t* __restrict__ attn_b,
                                                 bf16_t* __restrict__ retr_b) {
  __shared__ alignas(16) char smem[35840];
  int tid = threadIdx.x;
  if (blockIdx.x < 1024) {
    bf16_t* Ks = (bf16_t*)smem;                    //  9216 B
    bf16_t* Vt = (bf16_t*)(smem + 9216);           //  9216 B
    float*  Oa = (float*)(smem + 18432);           // 17408 B
    int blk = blockIdx.x;
    int tcb = blk & 31;
    int h = (blk >> 5) & 15;
    int b = blk >> 9;
    int t0 = tcb * 64;
    int wv = tid >> 6, lane = tid & 63;
    int l15 = lane & 15, quad = lane >> 4;
    int tq0 = t0 + wv * 16;
    int t = tq0 + l15;
    int lo = t - 256; if (lo < 0) lo = 0;

    const bf16_t* qptr = qb + (((size_t)(b * 2048 + t) * 16) + h) * 64;
    bf16x8 qf0 = *(const bf16x8*)(qptr + quad * 8);
    bf16x8 qf1 = *(const bf16x8*)(qptr + 32 + quad * 8);

    f32x4 acc[4] = {};
    float mrun = -1e30f, lrun = 0.f;

    for (int c = 0; c < 5; ++c) {
      int s0 = t0 - 256 + c * 64;
      __syncthreads();
      #pragma unroll
      for (int it = 0; it < 2; ++it) {
        int task = tid + it * 256;
        int key = task >> 3, dseg = task & 7;
        int s = s0 + key; s = s < 0 ? 0 : (s > 2047 ? 2047 : s);
        *(bf16x8*)&Ks[key * 72 + dseg * 8] =
          *(const bf16x8*)(kb + (((size_t)(b * 2048 + s) * 16) + h) * 64 + dseg * 8);
      }
      {
        int vseg = tid & 7, kp = tid >> 3;
        int sA = s0 + 2 * kp, sB = sA + 1;
        sA = sA < 0 ? 0 : (sA > 2047 ? 2047 : sA);
        sB = sB < 0 ? 0 : (sB > 2047 ? 2047 : sB);
        bf16x8 va = *(const bf16x8*)(vb + (((size_t)(b * 2048 + sA) * 16) + h) * 64 + vseg * 8);
        bf16x8 vbv = *(const bf16x8*)(vb + (((size_t)(b * 2048 + sB) * 16) + h) * 64 + vseg * 8);
        #pragma unroll
        for (int j = 0; j < 8; ++j) {
          union { bf16_t h2[2]; unsigned int u; } pk;
          pk.h2[0] = va[j]; pk.h2[1] = vbv[j];
          *(unsigned int*)&Vt[(vseg * 8 + j) * 72 + 2 * kp] = pk.u;
        }
      }
      __syncthreads();
      #pragma unroll
      for (int p = 0; p < 2; ++p) {
        int sbase = s0 + p * 32;
        if (sbase > tq0 + 15 || sbase + 31 < tq0 - 256 || sbase + 31 < 0) continue;
        int kl = p * 32;
        bf16x8 ka0  = *(const bf16x8*)&Ks[(kl + l15) * 72 + quad * 8];
        bf16x8 ka0b = *(const bf16x8*)&Ks[(kl + l15) * 72 + 32 + quad * 8];
        bf16x8 ka1  = *(const bf16x8*)&Ks[(kl + 16 + l15) * 72 + quad * 8];
        bf16x8 ka1b = *(const bf16x8*)&Ks[(kl + 16 + l15) * 72 + 32 + quad * 8];
        f32x4 c0 = {}, c1 = {};
        c0 = __builtin_amdgcn_mfma_f32_16x16x32_bf16(ka0,  qf0, c0, 0, 0, 0);
        c0 = __builtin_amdgcn_mfma_f32_16x16x32_bf16(ka0b, qf1, c0, 0, 0, 0);
        c1 = __builtin_amdgcn_mfma_f32_16x16x32_bf16(ka1,  qf0, c1, 0, 0, 0);
        c1 = __builtin_amdgcn_mfma_f32_16x16x32_bf16(ka1b, qf1, c1, 0, 0, 0);
        float p0[4], p1[4];
        float mx = -1e30f;
        #pragma unroll
        for (int r = 0; r < 4; ++r) {
          int sK0 = sbase + quad * 4 + r;
          int sK1 = sK0 + 16;
          float v0 = (sK0 >= lo && sK0 <= t) ? c0[r] * 0.125f : -1e30f;
          float v1 = (sK1 >= lo && sK1 <= t) ? c1[r] * 0.125f : -1e30f;
          p0[r] = v0; p1[r] = v1;
          mx = fmaxf(mx, fmaxf(v0, v1));
        }
        mx = fmaxf(mx, __shfl_xor(mx, 16));
        mx = fmaxf(mx, __shfl_xor(mx, 32));
        float mnew = fmaxf(mrun, mx);
        float alpha = __expf(mrun - mnew);
        float rs = 0.f;
        #pragma unroll
        for (int r = 0; r < 4; ++r) {
          float e0 = (p0[r] > -1e29f) ? __expf(p0[r] - mnew) : 0.f;
          float e1 = (p1[r] > -1e29f) ? __expf(p1[r] - mnew) : 0.f;
          p0[r] = e0; p1[r] = e1;
          rs += e0 + e1;
        }
        rs += __shfl_xor(rs, 16);
        rs += __shfl_xor(rs, 32);
        mrun = mnew;
        lrun = lrun * alpha + rs;
        #pragma unroll
        for (int vt = 0; vt < 4; ++vt)
          #pragma unroll
          for (int r = 0; r < 4; ++r) acc[vt][r] *= alpha;
        union { bf16x4 v; int2 i2; } pka, pkb;
        #pragma unroll
        for (int r = 0; r < 4; ++r) { pka.v[r] = (bf16_t)p0[r]; pkb.v[r] = (bf16_t)p1[r]; }
        int sel = quad >> 1;
        int base = l15 + ((quad & 1) << 5);
        int a0 = __shfl(pka.i2.x, base),      b0 = __shfl(pkb.i2.x, base);
        int a1 = __shfl(pka.i2.y, base),      b1 = __shfl(pkb.i2.y, base);
        int a2 = __shfl(pka.i2.x, base + 16), b2 = __shfl(pkb.i2.x, base + 16);
        int a3 = __shfl(pka.i2.y, base + 16), b3 = __shfl(pkb.i2.y, base + 16);
        union { int4 i4; bf16x8 v; } pf;
        pf.i4.x = sel ? b0 : a0;
        pf.i4.y = sel ? b1 : a1;
        pf.i4.z = sel ? b2 : a2;
        pf.i4.w = sel ? b3 : a3;
        #pragma unroll
        for (int vt = 0; vt < 4; ++vt) {
          bf16x8 vfr = *(const bf16x8*)&Vt[(vt * 16 + l15) * 72 + kl + quad * 8];
          acc[vt] = __builtin_amdgcn_mfma_f32_16x16x32_bf16(vfr, pf.v, acc[vt], 0, 0, 0);
        }
      }
    }
    float rl = 1.0f / lrun;
    float* myOs = Oa + wv * (16 * 68);
    #pragma unroll
    for (int vt = 0; vt < 4; ++vt)
      #pragma unroll
      for (int r = 0; r < 4; ++r)
        myOs[l15 * 68 + vt * 16 + quad * 4 + r] = acc[vt][r] * rl;
    __syncthreads();
    #pragma unroll
    for (int q = 0; q < 16; ++q) {
      float v = myOs[q * 68 + lane];
      attn_b[(size_t)(b * 2048 + tq0 + q) * 1024 + h * 64 + lane] = (bf16_t)v;
    }
  } else {
    float* G = (float*)smem;                       // 16384 B
    int blk = blockIdx.x - 1024;     // 256 = 2*16*8
    int tc = blk & 7;
    int h = (blk >> 3) & 15;
    int b = blk >> 7;
    const f32x4* gsrc = (const f32x4*)(gdn + (size_t)(b * 16 + h) * 4096);
    #pragma unroll
    for (int it = 0; it < 4; ++it)
      ((f32x4*)G)[tid + it * 256] = gsrc[tid + it * 256];
    __syncthreads();
    int t = tc * 256 + tid;
    int id = ids[b * 2048 + t] - 50250;
    bool valid = (id >= 0) && (id < 64);
    const bf16_t* qrow = qgb + (((size_t)(b * 2048 + t) * 16) + h) * 64;
    const float* krow = bank + (size_t)(h * 64 + (valid ? id : 0)) * 64;
    float acc[64];
    #pragma unroll
    for (int v = 0; v < 64; ++v) acc[v] = 0.f;
    for (int k = 0; k < 64; ++k) {
      float qv = valid ? krow[k] : (float)qrow[k];
      const f32x4* gr = (const f32x4*)&G[k * 64];
      #pragma unroll
      for (int i = 0; i < 16; ++i) {
        f32x4 gv = gr[i];
        acc[i * 4 + 0] += qv * gv[0];
        acc[i * 4 + 1] += qv * gv[1];
        acc[i * 4 + 2] += qv * gv[2];
        acc[i * 4 + 3] += qv * gv[3];
      }
    }
    float g = gm[b * 2048 + t];
    bf16_t* orow = retr_b + (size_t)(b * 2048 + t) * 1024 + h * 64;
    #pragma unroll
    for (int i = 0; i < 8; ++i) {
      bf16x8 ov;
      #pragma unroll
      for (int j = 0; j < 8; ++j) ov[j] = (bf16_t)(acc[i * 8 + j] * g);
      *(bf16x8*)(orow + i * 8) = ov;
    }
  }
}

// ---------------------------------------------------------------------------
extern "C" void kernel_launch(void* const* d_in, const int* in_sizes, int n_in,
                              void* d_out, int out_size, void* d_ws, size_t ws_size,
                              hipStream_t stream) {
  const float* x        = (const float*)d_in[0];
  const float* gdn      = (const float*)d_in[1];
  const int*   ids      = (const int*)d_in[2];
  const float* key_bank = (const float*)d_in[3];
  const float* norm_w   = (const float*)d_in[4];
  const float* wq       = (const float*)d_in[5];
  const float* wk       = (const float*)d_in[6];
  const float* wv       = (const float*)d_in[7];
  const float* wo       = (const float*)d_in[8];
  const float* w_gq     = (const float*)d_in[9];
  const float* w_ro     = (const float*)d_in[10];
  const float* w_gate   = (const float*)d_in[11];
  const float* b_gate   = (const float*)d_in[12];

  char* p = (char*)d_ws;
  auto alloc = [&](size_t bytes) { char* r = p; p += (bytes + 255) & ~(size_t)255; return r; };
  const size_t ACT = (size_t)4096 * 1024 * 2;   // bf16 activation (8.4 MB)
  const size_t WTB = (size_t)1024 * 1024 * 2;   // bf16 weight (2.1 MB)
  bf16_t* xn_b   = (bf16_t*)alloc(ACT);
  bf16_t* wq_b   = (bf16_t*)alloc(WTB);
  bf16_t* wk_b   = (bf16_t*)alloc(WTB);
  bf16_t* wv_b   = (bf16_t*)alloc(WTB);
  bf16_t* wgq_b  = (bf16_t*)alloc(WTB);
  bf16_t* wo_b   = (bf16_t*)alloc(WTB);         // pre-scaled by 0.3
  bf16_t* wro_b  = (bf16_t*)alloc(WTB);
  bf16_t* qb     = (bf16_t*)alloc(ACT);
  bf16_t* kb     = (bf16_t*)alloc(ACT);
  bf16_t* vb     = (bf16_t*)alloc(ACT);
  bf16_t* qgb    = (bf16_t*)alloc(ACT);
  bf16_t* attn_b = (bf16_t*)alloc(ACT);
  bf16_t* retr_b = (bf16_t*)alloc(ACT);
  float*  gmean  = (float*)alloc(4096 * 4);
  float2* rtab   = (float2*)alloc(2048 * 32 * sizeof(float2));

  CvtArgs ca;
  ca.s[0] = wq;   ca.d[0] = wq_b;   ca.scale[0] = 1.0f;
  ca.s[1] = wk;   ca.d[1] = wk_b;   ca.scale[1] = 1.0f;
  ca.s[2] = wv;   ca.d[2] = wv_b;   ca.scale[2] = 1.0f;
  ca.s[3] = w_gq; ca.d[3] = wgq_b;  ca.scale[3] = 1.0f;
  ca.s[4] = wo;   ca.d[4] = wo_b;   ca.scale[4] = 0.3f;
  ca.s[5] = w_ro; ca.d[5] = wro_b;  ca.scale[5] = 1.0f;
  prep_kernel<<<10496, 256, 0, stream>>>(ca, x, norm_w, w_gate, b_gate,
                                         xn_b, gmean, rtab);

  // q(rope), k(rope), v, q_g in one dispatch — m97 gload16 staging
  GemmCfg g4;
  g4.seg[0] = {xn_b, wq_b,  (void*)qb,  1};
  g4.seg[1] = {xn_b, wk_b,  (void*)kb,  1};
  g4.seg[2] = {xn_b, wv_b,  (void*)vb,  0};
  g4.seg[3] = {xn_b, wgq_b, (void*)qgb, 0};
  g4.rope = rtab;
  g4.x = nullptr;
  gemm_glds<<<dim3(32, 32), 256, 0, stream>>>(g4);

  attn_retr<<<1280, 256, 0, stream>>>(qb, kb, vb, qgb, ids, key_bank, gdn,
                                      gmean, attn_b, retr_b);

  // tail: d_out = x + attn@0.3wo^T + (g*retr)@wro^T (2 phases, K=2048,
  // atomic-free, pipelined VGPR staging), 256 blocks.
  GemmCfg gf;
  gf.seg[0] = {attn_b, wo_b,  d_out, 2};
  gf.seg[1] = {retr_b, wro_b, d_out, 2};
  gf.rope = nullptr;
  gf.x = x;
  gemm_pipe<2><<<dim3(8, 32), 256, 0, stream>>>(gf);
}